// Round 14
// baseline (24.175 us; speedup 1.0000x reference)
//
#include <hip/hip_runtime.h>
#include <stdint.h>

// LTI all-pass: cascade of 8 second-order all-pass sections (DF2T):
//   y = B2*x + s1 ; s1' = B1*(x-y) + s2 ; s2' = x - B2*y
// Cascade = z^-16 A(1/z)/A(z) = B(z)/A(z) with b = a[::-1] (the reference).
//
// Overlap-and-discard: mag <= sigmoid(1.3608)*0.99 = 0.7881 (hard bound).
// WARM=32: absmax 0.0156 measured (R8/R10/R12), 7x under 0.112 threshold.
//
// Round-14: single-variable A/B vs R10 (22.3us): LINEAR DMA sources +
// PADDED LDS instead of the XOR chunk swizzle. Suspect: csw permutes each
// DMA instruction's lane->address order (4-bit XOR shuffle inside 256B
// groups); if the TA coalescer fast-paths only monotonic runs, every
// staging inst degrades to 64 separate 16B requests -- a request-rate wall
// that vmcnt(0) exposes per wave (the unexplained ~14us).
// Now: DMA inst q reads x[g0 + 256q + 4*lane] (perfectly linear 1KB) into
// seg + 260q (16B pad per 1KB block). Chunk c -> float 260*(c>>6)+4*(c&63):
//   - compute b128 reads: 4-way bank conflict (1.58x on 40 ops, ~+0.4us)
//   - copy-out reads: stride-4 floats -> 2-way (free)
//   - csw VALU gone
// Everything else identical to R10: 17 x global_load_lds(16), register-
// staged compute, in-place write-back, coalesced dwordx4 copy-out,
// 2048 one-wave blocks, 17.7 KB LDS -> 8 blocks/CU -> 2 waves/SIMD.

#define NROOTS 8
#define BATCH  32
#define TLEN   262144
#define CHUNK  64                      // output floats per lane
#define WARM   32                      // discarded warm-up floats per lane
#define WAVE_WIN 4096                  // output floats per wave
#define PIECE_CH ((WAVE_WIN + WARM) / 4)   // 1032 valid 16B chunks
#define NQ     17                      // DMA16 instructions
#define QSTRIDE 260                    // floats per DMA block in LDS (256 + pad)
#define SEGF   (NQ * QSTRIDE)          // 4420 LDS floats = 17.7 KB
#define BPR    (TLEN / WAVE_WIN)       // 64 waves per row

// float index of 16B-chunk c in the padded LDS layout
__device__ __forceinline__ int laddr(int c) {
    return QSTRIDE * (c >> 6) + 4 * (c & 63);
}

__global__ __launch_bounds__(64) void allpass_kernel(
    const float* __restrict__ x,
    const float* __restrict__ mag_logits,
    const float* __restrict__ cos_logits,
    float* __restrict__ y)
{
    __shared__ float seg[SEGF];

    const int lane = threadIdx.x;      // 0..63
    const int brow = blockIdx.x >> 6;  // / BPR
    const int wcol = blockIdx.x & (BPR - 1);
    const bool first = (wcol == 0);
    const long g0f = (long)brow * TLEN + (long)wcol * WAVE_WIN - WARM;

    // coefficient loads first: latency hides under DMA issue
    const float mlv = mag_logits[lane & 7];
    const float clv = cos_logits[lane & 7];

    // ---- async staging: 17 x DMA16, LINEAR source (contiguous 1KB per
    //      inst -> maximal request merging), padded linear LDS dest ----
#pragma unroll
    for (int q = 0; q < NQ; ++q) {
        int c = 64 * q + lane;                       // global chunk index
        if (q == 0 && first) c = max(c, WARM / 4);   // never read before row
        if (q == NQ - 1)     c = min(c, PIECE_CH - 1);  // tail clamp, in-row
        __builtin_amdgcn_global_load_lds(
            (const __attribute__((address_space(1))) uint32_t*)(x + g0f + 4 * c),
            (__attribute__((address_space(3))) uint32_t*)(seg + QSTRIDE * q),
            16, 0, 0);
    }

    // ---- coefficients while DMA is in flight ----
    float mm  = 0.99f / (1.0f + expf(-mlv));
    float cc  = tanhf(clv);
    float b1v = -2.0f * mm * cc;
    float b2v = mm * mm;
    float B1[NROOTS], B2[NROOTS], s1[NROOTS], s2[NROOTS];
#pragma unroll
    for (int s = 0; s < NROOTS; ++s) {
        B1[s] = __shfl(b1v, s);
        B2[s] = __shfl(b2v, s);
        s1[s] = 0.0f; s2[s] = 0.0f;
    }

    // drain DMA (wave owns its whole LDS segment -> no barrier needed)
    asm volatile("s_waitcnt vmcnt(0)" ::: "memory");

    // zero history at row head: floats [0,32) = chunks 0..7 (q=0) -> linear
    if (first && lane < WARM) seg[lane] = 0.0f;

    auto step = [&](float v) -> float {
#pragma unroll
        for (int s = 0; s < NROOTS; ++s) {
            float o = fmaf(B2[s], v, s1[s]);
            s1[s] = fmaf(B1[s], v - o, s2[s]);
            s2[s] = fmaf(-B2[s], o, v);          // neg folds into VOP3 modifier
            v = o;
        }
        return v;
    };

    // lane l: window = piece chunks [16l, 16l+24); outputs chunks [16l+8, 16l+24).
    const int c0 = 16 * lane;
    float r[WARM + CHUNK];             // 96 floats, all indices static

    // ---- read entire window into registers: 24 x ds_read_b128 ----
#pragma unroll
    for (int t = 0; t < 24; ++t) {
        const float4 v = *reinterpret_cast<const float4*>(seg + laddr(c0 + t));
        r[4 * t + 0] = v.x; r[4 * t + 1] = v.y;
        r[4 * t + 2] = v.z; r[4 * t + 3] = v.w;
    }

    // ---- compute: 32 warm steps (discarded) + 64 output steps, in regs ----
#pragma unroll
    for (int i = 0; i < WARM; ++i) step(r[i]);
#pragma unroll
    for (int i = 0; i < CHUNK; ++i) r[WARM + i] = step(r[WARM + i]);

    // ---- write outputs back: 16 x ds_write_b128 (after ALL reads) ----
#pragma unroll
    for (int t = 8; t < 24; ++t) {
        float4 v;
        v.x = r[4 * t + 0]; v.y = r[4 * t + 1];
        v.z = r[4 * t + 2]; v.w = r[4 * t + 3];
        *reinterpret_cast<float4*>(seg + laddr(c0 + t)) = v;
    }

    // ---- copy-out: padded LDS reads (2-way), coalesced dwordx4 stores ----
    float* gdst = y + (size_t)brow * TLEN + (size_t)wcol * WAVE_WIN;
#pragma unroll
    for (int k = 0; k < 16; ++k) {
        const int oc = 64 * k + lane;            // output chunk, lanes contiguous
        const float4 v = *reinterpret_cast<const float4*>(seg + laddr(oc + WARM / 4));
        *reinterpret_cast<float4*>(gdst + 4 * oc) = v;
    }
}

extern "C" void kernel_launch(void* const* d_in, const int* in_sizes, int n_in,
                              void* d_out, int out_size, void* d_ws, size_t ws_size,
                              hipStream_t stream) {
    const float* ex = (const float*)d_in[0];
    const float* ml = (const float*)d_in[1];
    const float* cl = (const float*)d_in[2];
    float* yo = (float*)d_out;

    allpass_kernel<<<BATCH * BPR, 64, 0, stream>>>(ex, ml, cl, yo);
}

// Round 15
// 23.791 us; speedup vs baseline: 1.0162x; 1.0162x over previous
//
#include <hip/hip_runtime.h>
#include <stdint.h>

// LTI all-pass: cascade of 8 second-order all-pass sections (DF2T):
//   y = B2*x + s1 ; s1' = B1*(x-y) + s2 ; s2' = x - B2*y
// Cascade = z^-16 A(1/z)/A(z) = B(z)/A(z) with b = a[::-1] (the reference).
//
// Overlap-and-discard: mag <= sigmoid(1.3608)*0.99 = 0.7881 (hard bound).
// WARM=32: absmax 0.0156 measured (R8/R10/R12), 7x under 0.112 threshold.
//
// Round-15: single-variable A/B vs R14: REG-STAGING instead of
// global_load_lds. Theory: the LDS-DMA queue caps in-flight cachelines
// (~64/CU -> ~1MB chip-wide -> ~2.7 TB/s), matching the measured 2.87 TB/s
// beyond-L2 BW that has been flat across R7-R14. Regular vmem loads get
// VGPR-sized concurrency: 17 x global_load_dwordx4 in flight per wave
// (17KB), rolling per-use vmcnt (compiler-inserted) so each ds_write_b128
// drains only its own load. Everything else is R14 verbatim: linear
// sources, padded LDS (QSTRIDE=260), register-staged compute, in-place
// write-back, coalesced dwordx4 copy-out. 2048 one-wave blocks, 17.7 KB
// LDS -> ~9 blocks/CU -> 2 waves/SIMD.

#define NROOTS 8
#define BATCH  32
#define TLEN   262144
#define CHUNK  64                      // output floats per lane
#define WARM   32                      // discarded warm-up floats per lane
#define WAVE_WIN 4096                  // output floats per wave
#define PIECE_CH ((WAVE_WIN + WARM) / 4)   // 1032 valid 16B chunks
#define NQ     17                      // staging load instructions
#define QSTRIDE 260                    // floats per 1KB block in LDS (256 + pad)
#define SEGF   (NQ * QSTRIDE)          // 4420 LDS floats = 17.7 KB
#define BPR    (TLEN / WAVE_WIN)       // 64 waves per row

// float index of 16B-chunk c in the padded LDS layout
__device__ __forceinline__ int laddr(int c) {
    return QSTRIDE * (c >> 6) + 4 * (c & 63);
}

__global__ __launch_bounds__(64) void allpass_kernel(
    const float* __restrict__ x,
    const float* __restrict__ mag_logits,
    const float* __restrict__ cos_logits,
    float* __restrict__ y)
{
    __shared__ float seg[SEGF];

    const int lane = threadIdx.x;      // 0..63
    const int brow = blockIdx.x >> 6;  // / BPR
    const int wcol = blockIdx.x & (BPR - 1);
    const bool first = (wcol == 0);
    const long g0f = (long)brow * TLEN + (long)wcol * WAVE_WIN - WARM;

    // ---- staging loads: 17 x global_load_dwordx4, ALL in flight ----
    // (normal vmem path: concurrency limited only by VGPRs, not the
    // LDS-DMA queue). Linear 1KB span per instruction, fully coalesced.
    float4 tmp[NQ];
#pragma unroll
    for (int q = 0; q < NQ; ++q) {
        int c = 64 * q + lane;                       // global chunk index
        if (q == 0 && first) c = max(c, WARM / 4);   // never read before row
        if (q == NQ - 1)     c = min(c, PIECE_CH - 1);  // tail clamp, in-row
        tmp[q] = *reinterpret_cast<const float4*>(x + g0f + 4 * c);
    }

    // ---- coefficients while loads are in flight ----
    const float mlv = mag_logits[lane & 7];
    const float clv = cos_logits[lane & 7];
    float mm  = 0.99f / (1.0f + expf(-mlv));
    float cc  = tanhf(clv);
    float b1v = -2.0f * mm * cc;
    float b2v = mm * mm;
    float B1[NROOTS], B2[NROOTS], s1[NROOTS], s2[NROOTS];
#pragma unroll
    for (int s = 0; s < NROOTS; ++s) {
        B1[s] = __shfl(b1v, s);
        B2[s] = __shfl(b2v, s);
        s1[s] = 0.0f; s2[s] = 0.0f;
    }

    // ---- LDS writes: compiler inserts rolling vmcnt(N) so write q waits
    //      only for load q; later writes drain under earlier loads ----
#pragma unroll
    for (int q = 0; q < NQ; ++q) {
        *reinterpret_cast<float4*>(seg + QSTRIDE * q + 4 * lane) = tmp[q];
    }

    // zero history at row head: floats [0,32) = chunks 0..7 (q=0) -> linear
    if (first && lane < WARM) seg[lane] = 0.0f;

    auto step = [&](float v) -> float {
#pragma unroll
        for (int s = 0; s < NROOTS; ++s) {
            float o = fmaf(B2[s], v, s1[s]);
            s1[s] = fmaf(B1[s], v - o, s2[s]);
            s2[s] = fmaf(-B2[s], o, v);          // neg folds into VOP3 modifier
            v = o;
        }
        return v;
    };

    // lane l: window = piece chunks [16l, 16l+24); outputs chunks [16l+8, 16l+24).
    const int c0 = 16 * lane;
    float r[WARM + CHUNK];             // 96 floats, all indices static

    // ---- read entire window into registers: 24 x ds_read_b128 ----
#pragma unroll
    for (int t = 0; t < 24; ++t) {
        const float4 v = *reinterpret_cast<const float4*>(seg + laddr(c0 + t));
        r[4 * t + 0] = v.x; r[4 * t + 1] = v.y;
        r[4 * t + 2] = v.z; r[4 * t + 3] = v.w;
    }

    // ---- compute: 32 warm steps (discarded) + 64 output steps, in regs ----
#pragma unroll
    for (int i = 0; i < WARM; ++i) step(r[i]);
#pragma unroll
    for (int i = 0; i < CHUNK; ++i) r[WARM + i] = step(r[WARM + i]);

    // ---- write outputs back: 16 x ds_write_b128 (after ALL reads) ----
#pragma unroll
    for (int t = 8; t < 24; ++t) {
        float4 v;
        v.x = r[4 * t + 0]; v.y = r[4 * t + 1];
        v.z = r[4 * t + 2]; v.w = r[4 * t + 3];
        *reinterpret_cast<float4*>(seg + laddr(c0 + t)) = v;
    }

    // ---- copy-out: padded LDS reads (2-way), coalesced dwordx4 stores ----
    float* gdst = y + (size_t)brow * TLEN + (size_t)wcol * WAVE_WIN;
#pragma unroll
    for (int k = 0; k < 16; ++k) {
        const int oc = 64 * k + lane;            // output chunk, lanes contiguous
        const float4 v = *reinterpret_cast<const float4*>(seg + laddr(oc + WARM / 4));
        *reinterpret_cast<float4*>(gdst + 4 * oc) = v;
    }
}

extern "C" void kernel_launch(void* const* d_in, const int* in_sizes, int n_in,
                              void* d_out, int out_size, void* d_ws, size_t ws_size,
                              hipStream_t stream) {
    const float* ex = (const float*)d_in[0];
    const float* ml = (const float*)d_in[1];
    const float* cl = (const float*)d_in[2];
    float* yo = (float*)d_out;

    allpass_kernel<<<BATCH * BPR, 64, 0, stream>>>(ex, ml, cl, yo);
}

// Round 16
// 21.862 us; speedup vs baseline: 1.1058x; 1.0883x over previous
//
#include <hip/hip_runtime.h>
#include <stdint.h>

// LTI all-pass: cascade of 8 second-order all-pass sections (DF2T):
//   y = B2*x + s1 ; s1' = B1*(x-y) + s2 ; s2' = x - B2*y
// Cascade = z^-16 A(1/z)/A(z) = B(z)/A(z) with b = a[::-1] (the reference).
//
// Overlap-and-discard: mag <= sigmoid(1.3608)*0.99 = 0.7881 (hard bound).
// WARM=32: absmax 0.0156 measured (R8/R10/R12), 7x under 0.112 threshold.
//
// Round-16: R10 (best, 22.3us) + GENERATION STAGGER. Hypothesis: all 2048
// resident waves issue loads at t=0; the memory system interleaves every
// wave's requests, so ALL waves' windows complete near the end of the
// aggregate transfer -> grid-wide load convoy, then compute convoy, then
// store convoy (additive ~17us fixed part; slope-1 in compute work --
// fits R7-R15). Fix: block generation g=(blockIdx>>8)&7 sleeps g*~0.64us
// before issuing its DMA. Breadth-first dispatch puts generations 0..7 on
// each CU -> waves within a CU are phase-shifted: gen k's compute+stores
// overlap gen k+1's loads; R/W streams pipeline toward the 67MB/6.3TB/s
// ~10.6us traffic floor.
// Everything else R10 verbatim: 17 x global_load_lds(16), chunk-XOR
// swizzle csw(c)=c^((c>>4)&15) (linear LDS dest, pre-swizzled source),
// register-staged compute, in-place write-back, coalesced dwordx4
// copy-out. 2048 one-wave blocks, 17 KB LDS -> 8 blocks/CU -> 2 w/SIMD.

#define NROOTS 8
#define BATCH  32
#define TLEN   262144
#define CHUNK  64                      // output floats per lane
#define WARM   32                      // discarded warm-up floats per lane
#define WAVE_WIN 4096                  // output floats per wave
#define PIECE_CH ((WAVE_WIN + WARM) / 4)   // 1032 valid 16B chunks
#define NQ     17                      // DMA16 instructions
#define SEGF   (NQ * 256)              // 4352 LDS floats = 17 KB
#define BPR    (TLEN / WAVE_WIN)       // 64 waves per row

__device__ __forceinline__ int csw(int c) { return c ^ ((c >> 4) & 15); }

__global__ __launch_bounds__(64) void allpass_kernel(
    const float* __restrict__ x,
    const float* __restrict__ mag_logits,
    const float* __restrict__ cos_logits,
    float* __restrict__ y)
{
    __shared__ float seg[SEGF];

    const int lane = threadIdx.x;      // 0..63
    const int brow = blockIdx.x >> 6;  // / BPR
    const int wcol = blockIdx.x & (BPR - 1);
    const bool first = (wcol == 0);
    const long g0f = (long)brow * TLEN + (long)wcol * WAVE_WIN - WARM;

    // ---- generation stagger: gen = dispatch generation (breadth-first:
    //      CU c hosts blocks c, c+256, ... -> gens 0..7 per CU). Each
    //      s_sleep 24 ~ 24*64 cyc ~ 0.64us; gen g delays g slots so its
    //      load burst lands as gen g-1 moves to compute.
    {
        const int gen = (blockIdx.x >> 8) & 7;
        for (int i = 0; i < gen; ++i)
            asm volatile("s_sleep 24");
    }

    // coefficient loads: latency hides under DMA issue
    const float mlv = mag_logits[lane & 7];
    const float clv = cos_logits[lane & 7];

    // ---- async staging: 17 x DMA16 (R10 verbatim). Slot chunk s holds
    //      global chunk csw(s); LDS dest linear, source pre-swizzled. ----
#pragma unroll
    for (int q = 0; q < NQ; ++q) {
        int sc = csw(64 * q + lane);
        if (q == 0 && first) sc = max(sc, WARM / 4);     // never read before row
        if (q == NQ - 1)     sc = min(sc, PIECE_CH - 1); // tail clamp, in-row
        __builtin_amdgcn_global_load_lds(
            (const __attribute__((address_space(1))) uint32_t*)(x + g0f + 4 * sc),
            (__attribute__((address_space(3))) uint32_t*)(seg + 256 * q),
            16, 0, 0);
    }

    // ---- coefficients while DMA is in flight ----
    float mm  = 0.99f / (1.0f + expf(-mlv));
    float cc  = tanhf(clv);
    float b1v = -2.0f * mm * cc;
    float b2v = mm * mm;
    float B1[NROOTS], B2[NROOTS], s1[NROOTS], s2[NROOTS];
#pragma unroll
    for (int s = 0; s < NROOTS; ++s) {
        B1[s] = __shfl(b1v, s);
        B2[s] = __shfl(b2v, s);
        s1[s] = 0.0f; s2[s] = 0.0f;
    }

    // drain DMA (wave owns its whole LDS segment -> no barrier needed)
    asm volatile("s_waitcnt vmcnt(0)" ::: "memory");

    // zero history at row head: floats [0,32) = chunks 0..7, csw(c)=c -> linear
    if (first && lane < WARM) seg[lane] = 0.0f;

    auto step = [&](float v) -> float {
#pragma unroll
        for (int s = 0; s < NROOTS; ++s) {
            float o = fmaf(B2[s], v, s1[s]);
            s1[s] = fmaf(B1[s], v - o, s2[s]);
            s2[s] = fmaf(-B2[s], o, v);          // neg folds into VOP3 modifier
            v = o;
        }
        return v;
    };

    // lane l: window = piece chunks [16l, 16l+24); outputs chunks [16l+8, 16l+24).
    const int c0 = 16 * lane;
    float r[WARM + CHUNK];             // 96 floats, all indices static

    // ---- read entire window into registers: 24 x ds_read_b128 ----
#pragma unroll
    for (int t = 0; t < 24; ++t) {
        const int sl = csw(c0 + t);
        const float4 v = *reinterpret_cast<const float4*>(seg + 4 * sl);
        r[4 * t + 0] = v.x; r[4 * t + 1] = v.y;
        r[4 * t + 2] = v.z; r[4 * t + 3] = v.w;
    }

    // ---- compute: 32 warm steps (discarded) + 64 output steps, in regs ----
#pragma unroll
    for (int i = 0; i < WARM; ++i) step(r[i]);
#pragma unroll
    for (int i = 0; i < CHUNK; ++i) r[WARM + i] = step(r[WARM + i]);

    // ---- write outputs back: 16 x ds_write_b128 (after ALL reads) ----
#pragma unroll
    for (int t = 8; t < 24; ++t) {
        const int sl = csw(c0 + t);
        float4 v;
        v.x = r[4 * t + 0]; v.y = r[4 * t + 1];
        v.z = r[4 * t + 2]; v.w = r[4 * t + 3];
        *reinterpret_cast<float4*>(seg + 4 * sl) = v;
    }

    // ---- copy-out: swizzled LDS reads (~2-way), coalesced dwordx4 stores ----
    float* gdst = y + (size_t)brow * TLEN + (size_t)wcol * WAVE_WIN;
#pragma unroll
    for (int k = 0; k < 16; ++k) {
        const int oc = 64 * k + lane;            // output chunk, lanes contiguous
        const int sl = csw(oc + WARM / 4);
        const float4 v = *reinterpret_cast<const float4*>(seg + 4 * sl);
        *reinterpret_cast<float4*>(gdst + 4 * oc) = v;
    }
}

extern "C" void kernel_launch(void* const* d_in, const int* in_sizes, int n_in,
                              void* d_out, int out_size, void* d_ws, size_t ws_size,
                              hipStream_t stream) {
    const float* ex = (const float*)d_in[0];
    const float* ml = (const float*)d_in[1];
    const float* cl = (const float*)d_in[2];
    float* yo = (float*)d_out;

    allpass_kernel<<<BATCH * BPR, 64, 0, stream>>>(ex, ml, cl, yo);
}